// Round 7
// baseline (198.106 us; speedup 1.0000x reference)
//
#include <hip/hip_runtime.h>
#include <math.h>

typedef float f32x4 __attribute__((ext_vector_type(4)));

// Problem constants (fixed by setup_inputs)
#define D_MODEL   2048
#define N_ROWS    32768      // B*L
#define D_ALIGN   512
#define D_REG     256
#define N_REG     3
#define REG_FLAT  1536
#define EPSF      1e-8f

#define PA_N   (D_ALIGN * REG_FLAT)   // 786432
#define PD_N   (D_ALIGN * D_MODEL)    // 1048576
#define W_N    (D_REG * D_MODEL)      // 524288

// Output layout (flat f32): gated_delta | updated_registers | gate | wg
#define OUT_REGS  ((size_t)N_ROWS * D_MODEL)
#define OUT_GATE  (OUT_REGS + REG_FLAT)
#define OUT_WG    (OUT_GATE + 1)

// ws layout (floats)
#define WS_SUMS      0      // 2048 column sums of delta
#define WS_ABSP      2048   // 256 abs-sum partials: 8 matrices x 32 chunks
#define WS_REGPROJ   2304   // 512
#define WS_DELTAPROJ 2816   // 512
#define WS_UPD       3328   // 1536 (real 0..768, imag 768..1536)
#define WS_WG        4864   // 3
#define WS_PART      8192   // column-sum partials [NBY][2048]
#define NBY          512
#define WS_REQ_BYTES ((size_t)(WS_PART + NBY * D_MODEL) * sizeof(float))

#define TOTAL_ROWS    2563

__device__ __forceinline__ float bfly(float v) {
    #pragma unroll
    for (int o = 32; o > 0; o >>= 1) v += __shfl_xor(v, o, 64);
    return v;   // total in ALL lanes
}

// ---------- Kernel 1: colsum partials (blocks 0..511) + absmean partials (512..767) ----------
// delta: NT loads (re-use via L3 is proven hopeless -> don't churn caches).
// weights: PLAIN loads (they ARE re-read by k_matvec right after -> warm L3).
__global__ __launch_bounds__(256) void k_stage1(const float* __restrict__ delta,
                                                const float* __restrict__ pa,
                                                const float* __restrict__ pd,
                                                const float* __restrict__ wr,
                                                const float* __restrict__ wi,
                                                const int* __restrict__ pidx,
                                                float* __restrict__ ws,
                                                int use_part) {
    const int b = blockIdx.x, t = threadIdx.x;
    if (b < NBY) {
        const f32x4* p = (const f32x4*)(delta + (size_t)b * 64 * D_MODEL);
        f32x4 a0  = {0.f, 0.f, 0.f, 0.f};
        f32x4 a0b = {0.f, 0.f, 0.f, 0.f};
        f32x4 a1  = {0.f, 0.f, 0.f, 0.f};
        f32x4 a1b = {0.f, 0.f, 0.f, 0.f};
        #pragma unroll 8
        for (int r = 0; r < 64; r += 2) {
            a0  += __builtin_nontemporal_load(&p[r * 512 + t]);
            a1  += __builtin_nontemporal_load(&p[r * 512 + t + 256]);
            a0b += __builtin_nontemporal_load(&p[(r + 1) * 512 + t]);
            a1b += __builtin_nontemporal_load(&p[(r + 1) * 512 + t + 256]);
        }
        a0 += a0b; a1 += a1b;
        if (use_part) {
            f32x4* part = (f32x4*)(ws + WS_PART);
            part[(size_t)b * 512 + t]       = a0;
            part[(size_t)b * 512 + t + 256] = a1;
        } else {
            atomicAdd(&ws[WS_SUMS + t * 4 + 0], a0.x);
            atomicAdd(&ws[WS_SUMS + t * 4 + 1], a0.y);
            atomicAdd(&ws[WS_SUMS + t * 4 + 2], a0.z);
            atomicAdd(&ws[WS_SUMS + t * 4 + 3], a0.w);
            atomicAdd(&ws[WS_SUMS + (t + 256) * 4 + 0], a1.x);
            atomicAdd(&ws[WS_SUMS + (t + 256) * 4 + 1], a1.y);
            atomicAdd(&ws[WS_SUMS + (t + 256) * 4 + 2], a1.z);
            atomicAdd(&ws[WS_SUMS + (t + 256) * 4 + 3], a1.w);
        }
    } else {
        const int idx = b - NBY;           // 0..255
        // zero WS_SUMS for k_reduce's atomic finish (visible at next dispatch)
        if (use_part && idx == 0) {
            for (int i = t; i < D_MODEL; i += 256) ws[WS_SUMS + i] = 0.f;
        }
        const int m = idx >> 5, chunk = idx & 31;
        const int pp = *pidx;
        const float* base; int n4;
        if (m == 0)      { base = pa + (size_t)pp * PA_N;                n4 = PA_N / 4; }
        else if (m == 1) { base = pd + (size_t)pp * PD_N;                n4 = PD_N / 4; }
        else if (m < 5)  { base = wr + (size_t)(pp * 3 + (m - 2)) * W_N; n4 = W_N / 4; }
        else             { base = wi + (size_t)(pp * 3 + (m - 5)) * W_N; n4 = W_N / 4; }
        const int per = n4 / 32;
        const int s = chunk * per, e = s + per;
        float acc = 0.f;
        for (int i = s + t; i < e; i += 256) {
            f32x4 v = ((const f32x4*)base)[i];     // plain: warm L3 for k_matvec
            acc += fabsf(v.x) + fabsf(v.y) + fabsf(v.z) + fabsf(v.w);
        }
        acc = bfly(acc);
        __shared__ float sh[4];
        if ((t & 63) == 0) sh[t >> 6] = acc;
        __syncthreads();
        if (t == 0) ws[WS_ABSP + idx] = sh[0] + sh[1] + sh[2] + sh[3];
    }
}

// ---------- Kernel 2 (partial path only): reduce partials -> column sums ----------
// grid (8,8): 64 blocks, each sums 64 partial rows for 256 cols, atomic finish.
__global__ __launch_bounds__(256) void k_reduce(float* __restrict__ ws) {
    const int col = blockIdx.x * 256 + threadIdx.x;
    const float* part = ws + WS_PART + (size_t)blockIdx.y * 64 * D_MODEL;
    float a0 = 0.f, a1 = 0.f, a2 = 0.f, a3 = 0.f;
    #pragma unroll 8
    for (int p = 0; p < 64; p += 4) {
        a0 += part[(size_t)(p + 0) * D_MODEL + col];
        a1 += part[(size_t)(p + 1) * D_MODEL + col];
        a2 += part[(size_t)(p + 2) * D_MODEL + col];
        a3 += part[(size_t)(p + 3) * D_MODEL + col];
    }
    atomicAdd(&ws[WS_SUMS + col], (a0 + a1) + (a2 + a3));
}

// ---------- Kernel 3: all matvecs, one wave per row ----------
// rows: [0,512) reg_proj | [512,1024) delta_proj | [1024,2560) upd (r then i) | [2560,2563) wg
__global__ __launch_bounds__(256) void k_matvec(const float* __restrict__ regs,
                                                const float* __restrict__ pa,
                                                const float* __restrict__ pd,
                                                const float* __restrict__ wr,
                                                const float* __restrict__ wi,
                                                const float* __restrict__ wgw,
                                                const float* __restrict__ wgb,
                                                const int* __restrict__ pidx,
                                                float* __restrict__ ws) {
    const int wid = threadIdx.x >> 6, lane = threadIdx.x & 63;
    const int row = blockIdx.x * 4 + wid;
    if (row >= TOTAL_ROWS) return;
    const int p = *pidx;

    const float* w; const float* x; int n4; int outIdx;
    float s = 0.f, post, bias = 0.f;
    bool tern = true;

    if (row < 512) {
        w = pa + (size_t)p * PA_N + (size_t)row * REG_FLAT;
        x = regs; n4 = REG_FLAT / 4;
        float a = (lane < 32) ? ws[WS_ABSP + lane] : 0.f;
        s = bfly(a) / (float)PA_N + EPSF;
        float q = 0.f;
        for (int i = lane; i < REG_FLAT / 4; i += 64) {
            f32x4 v = ((const f32x4*)regs)[i];
            q += v.x * v.x + v.y * v.y + v.z * v.z + v.w * v.w;
        }
        post = s / (sqrtf(bfly(q)) + EPSF);
        outIdx = WS_REGPROJ + row;
    } else if (row < 1024) {
        const int o = row - 512;
        w = pd + (size_t)p * PD_N + (size_t)o * D_MODEL;
        x = ws + WS_SUMS; n4 = D_MODEL / 4;
        float a = (lane < 32) ? ws[WS_ABSP + 32 + lane] : 0.f;
        s = bfly(a) / (float)PD_N + EPSF;
        float q = 0.f;
        for (int i = lane; i < D_MODEL / 4; i += 64) {
            f32x4 v = ((const f32x4*)(ws + WS_SUMS))[i];
            q += v.x * v.x + v.y * v.y + v.z * v.z + v.w * v.w;
        }
        // Wq @ (summary/(||summary||+eps)) == dot_q * s / (||sums|| + N*eps)
        post = s / (sqrtf(bfly(q)) + (float)N_ROWS * EPSF);
        outIdx = WS_DELTAPROJ + o;
    } else if (row < 2560) {
        const int t = row - 1024;                 // 0..1535
        const int half = t >= 768 ? 1 : 0;        // 0=real,1=imag
        const int tt = t - half * 768;            // 0..767
        const int r = tt >> 8;
        const int m = 2 + half * 3 + r;
        w = (half ? wi : wr) + (size_t)(p * 3 + r) * W_N + (size_t)(tt & 255) * D_MODEL;
        x = ws + WS_SUMS; n4 = D_MODEL / 4;
        float a = (lane < 32) ? ws[WS_ABSP + m * 32 + lane] : 0.f;
        s = bfly(a) / (float)W_N + EPSF;
        post = s / (float)N_ROWS;                 // summary = sums/N
        outIdx = WS_UPD + t;
    } else {
        const int i = row - 2560;
        const int mm = p * 3 + i;
        w = wgw + (size_t)mm * D_MODEL;
        x = ws + WS_SUMS; n4 = D_MODEL / 4;
        tern = false;
        post = 1.f / (float)N_ROWS;
        bias = wgb[mm];
        outIdx = WS_WG + i;
    }

    float acc = 0.f;
    if (tern) {
        const float inv_s = 1.0f / s;      // wave-uniform; replaces 4 divides/iter
        for (int i = lane; i < n4; i += 64) {
            f32x4 wv = __builtin_nontemporal_load(&((const f32x4*)w)[i]);
            f32x4 xv = ((const f32x4*)x)[i];
            float q0 = fmaxf(-1.f, fminf(1.f, rintf(wv.x * inv_s)));
            float q1 = fmaxf(-1.f, fminf(1.f, rintf(wv.y * inv_s)));
            float q2 = fmaxf(-1.f, fminf(1.f, rintf(wv.z * inv_s)));
            float q3 = fmaxf(-1.f, fminf(1.f, rintf(wv.w * inv_s)));
            acc += q0 * xv.x + q1 * xv.y + q2 * xv.z + q3 * xv.w;
        }
    } else {
        for (int i = lane; i < n4; i += 64) {
            f32x4 wv = __builtin_nontemporal_load(&((const f32x4*)w)[i]);
            f32x4 xv = ((const f32x4*)x)[i];
            acc += wv.x * xv.x + wv.y * xv.y + wv.z * xv.z + wv.w * xv.w;
        }
    }
    acc = bfly(acc);
    if (lane == 0) ws[outIdx] = acc * post + bias;
}

// ---------- Kernel 4: gated_delta = gate * delta (NT load, NT store, fwd) ----------
// Finalize fused into block 0. All ws inputs were written by PREVIOUS kernels
// (dispatch boundary = coherent); every block recomputes gate locally (cheap).
__global__ __launch_bounds__(256) void k_scale(const f32x4* __restrict__ in,
                                               f32x4* __restrict__ out4,
                                               const float* __restrict__ ws,
                                               const float* __restrict__ regs,
                                               const float* __restrict__ temp,
                                               const float* __restrict__ lbias,
                                               const int* __restrict__ pidx,
                                               float* __restrict__ out) {
    const int tid = threadIdx.x;
    float a = 0.f;
    for (int i = tid; i < D_ALIGN; i += 256)
        a += ws[WS_REGPROJ + i] * ws[WS_DELTAPROJ + i];
    a = bfly(a);
    __shared__ float sh[4];
    if ((tid & 63) == 0) sh[tid >> 6] = a;
    __syncthreads();
    const int p = *pidx;
    const float align = sh[0] + sh[1] + sh[2] + sh[3];
    const float g = 1.f / (1.f + expf(-(align * temp[p] + lbias[p])));

    if (blockIdx.x == 0) {
        __shared__ float wg_s[N_REG];
        if (tid == 0) out[OUT_GATE] = g;
        if (tid < N_REG) {
            float v = 1.f / (1.f + expf(-ws[WS_WG + tid]));
            wg_s[tid] = v;
            out[OUT_WG + tid] = v;
        }
        __syncthreads();
        for (int t = tid; t < REG_FLAT; t += 256) {
            const int rk = t >> 1, c = t & 1;
            float u = ws[WS_UPD + c * 768 + rk];
            out[OUT_REGS + t] = regs[t] + wg_s[rk >> 8] * u;
        }
    }

    const size_t stride = (size_t)gridDim.x * 256;   // 524288 threads
    const size_t linear = (size_t)blockIdx.x * 256 + tid;
    #pragma unroll 8
    for (int j = 0; j < 32; ++j) {                   // 32 * 524288 * 4 = 64M floats
        const size_t i = linear + (size_t)j * stride;
        f32x4 v = __builtin_nontemporal_load(&in[i]);
        v *= g;
        __builtin_nontemporal_store(v, &out4[i]);
    }
}

extern "C" void kernel_launch(void* const* d_in, const int* in_sizes, int n_in,
                              void* d_out, int out_size, void* d_ws, size_t ws_size,
                              hipStream_t stream) {
    (void)in_sizes; (void)n_in; (void)out_size;
    const float* delta = (const float*)d_in[0];
    const float* regs  = (const float*)d_in[1];
    const float* pa    = (const float*)d_in[2];
    const float* pd    = (const float*)d_in[3];
    const float* temp  = (const float*)d_in[4];
    const float* lbias = (const float*)d_in[5];
    const float* wr    = (const float*)d_in[6];
    const float* wi    = (const float*)d_in[7];
    const float* wgw   = (const float*)d_in[8];
    const float* wgb   = (const float*)d_in[9];
    const int*   pidx  = (const int*)d_in[10];
    float* out = (float*)d_out;
    float* ws  = (float*)d_ws;

    const int use_part = (ws_size >= WS_REQ_BYTES) ? 1 : 0;
    if (!use_part)
        hipMemsetAsync(d_ws, 0, D_MODEL * sizeof(float), stream);  // zero column sums

    k_stage1<<<NBY + 256, 256, 0, stream>>>(delta, pa, pd, wr, wi, pidx, ws, use_part);
    if (use_part)
        k_reduce<<<dim3(8, 8), 256, 0, stream>>>(ws);
    k_matvec<<<(TOTAL_ROWS + 3) / 4, 256, 0, stream>>>(regs, pa, pd, wr, wi,
                                                       wgw, wgb, pidx, ws);
    k_scale<<<2048, 256, 0, stream>>>((const f32x4*)delta, (f32x4*)d_out, ws,
                                      regs, temp, lbias, pidx, out);
}

// Round 8
// 164.207 us; speedup vs baseline: 1.2064x; 1.2064x over previous
//
#include <hip/hip_runtime.h>
#include <math.h>

typedef float f32x4 __attribute__((ext_vector_type(4)));

// Problem constants (fixed by setup_inputs)
#define D_MODEL   2048
#define N_ROWS    32768      // B*L
#define D_ALIGN   512
#define D_REG     256
#define N_REG     3
#define REG_FLAT  1536
#define EPSF      1e-8f

#define PA_N   (D_ALIGN * REG_FLAT)   // 786432
#define PD_N   (D_ALIGN * D_MODEL)    // 1048576
#define W_N    (D_REG * D_MODEL)      // 524288

// Output layout (flat f32): gated_delta | updated_registers | gate | wg
#define OUT_REGS  ((size_t)N_ROWS * D_MODEL)
#define OUT_GATE  (OUT_REGS + REG_FLAT)
#define OUT_WG    (OUT_GATE + 1)

// ws layout (floats)
#define WS_SUMS      0      // 2048 column sums of delta
#define WS_ABSP      2048   // 256 abs-sum partials: 8 matrices x 32 chunks
#define WS_REGPROJ   2304   // 512
#define WS_DELTAPROJ 2816   // 512
#define WS_UPD       3328   // 1536 (real 0..768, imag 768..1536)
#define WS_WG        4864   // 3
#define WS_PART      8192   // column-sum partials [NBY][2048]
#define NBY          512
#define WS_REQ_BYTES ((size_t)(WS_PART + NBY * D_MODEL) * sizeof(float))

#define TOTAL_ROWS    2563

__device__ __forceinline__ float bfly(float v) {
    #pragma unroll
    for (int o = 32; o > 0; o >>= 1) v += __shfl_xor(v, o, 64);
    return v;   // total in ALL lanes
}

// ---------- Kernel 1: colsum partials (blocks 0..511) + absmean partials (512..767) ----------
// delta: PLAIN loads (NT loads measured 2.5 TB/s in R7 — never again on streams).
// weights: PLAIN loads (they ARE re-read by k_matvec right after -> warm L3).
__global__ __launch_bounds__(256) void k_stage1(const float* __restrict__ delta,
                                                const float* __restrict__ pa,
                                                const float* __restrict__ pd,
                                                const float* __restrict__ wr,
                                                const float* __restrict__ wi,
                                                const int* __restrict__ pidx,
                                                float* __restrict__ ws,
                                                int use_part) {
    const int b = blockIdx.x, t = threadIdx.x;
    if (b < NBY) {
        const f32x4* p = (const f32x4*)(delta + (size_t)b * 64 * D_MODEL);
        f32x4 a0  = {0.f, 0.f, 0.f, 0.f};
        f32x4 a0b = {0.f, 0.f, 0.f, 0.f};
        f32x4 a1  = {0.f, 0.f, 0.f, 0.f};
        f32x4 a1b = {0.f, 0.f, 0.f, 0.f};
        #pragma unroll 8
        for (int r = 0; r < 64; r += 2) {
            a0  += p[r * 512 + t];
            a1  += p[r * 512 + t + 256];
            a0b += p[(r + 1) * 512 + t];
            a1b += p[(r + 1) * 512 + t + 256];
        }
        a0 += a0b; a1 += a1b;
        if (use_part) {
            f32x4* part = (f32x4*)(ws + WS_PART);
            part[(size_t)b * 512 + t]       = a0;
            part[(size_t)b * 512 + t + 256] = a1;
        } else {
            atomicAdd(&ws[WS_SUMS + t * 4 + 0], a0.x);
            atomicAdd(&ws[WS_SUMS + t * 4 + 1], a0.y);
            atomicAdd(&ws[WS_SUMS + t * 4 + 2], a0.z);
            atomicAdd(&ws[WS_SUMS + t * 4 + 3], a0.w);
            atomicAdd(&ws[WS_SUMS + (t + 256) * 4 + 0], a1.x);
            atomicAdd(&ws[WS_SUMS + (t + 256) * 4 + 1], a1.y);
            atomicAdd(&ws[WS_SUMS + (t + 256) * 4 + 2], a1.z);
            atomicAdd(&ws[WS_SUMS + (t + 256) * 4 + 3], a1.w);
        }
    } else {
        const int idx = b - NBY;           // 0..255
        // zero WS_SUMS for k_reduce's atomic finish (visible at next dispatch)
        if (use_part && idx == 0) {
            for (int i = t; i < D_MODEL; i += 256) ws[WS_SUMS + i] = 0.f;
        }
        const int m = idx >> 5, chunk = idx & 31;
        const int pp = *pidx;
        const float* base; int n4;
        if (m == 0)      { base = pa + (size_t)pp * PA_N;                n4 = PA_N / 4; }
        else if (m == 1) { base = pd + (size_t)pp * PD_N;                n4 = PD_N / 4; }
        else if (m < 5)  { base = wr + (size_t)(pp * 3 + (m - 2)) * W_N; n4 = W_N / 4; }
        else             { base = wi + (size_t)(pp * 3 + (m - 5)) * W_N; n4 = W_N / 4; }
        const int per = n4 / 32;
        const int s = chunk * per, e = s + per;
        float acc = 0.f;
        for (int i = s + t; i < e; i += 256) {
            f32x4 v = ((const f32x4*)base)[i];     // plain: warm L3 for k_matvec
            acc += fabsf(v.x) + fabsf(v.y) + fabsf(v.z) + fabsf(v.w);
        }
        acc = bfly(acc);
        __shared__ float sh[4];
        if ((t & 63) == 0) sh[t >> 6] = acc;
        __syncthreads();
        if (t == 0) ws[WS_ABSP + idx] = sh[0] + sh[1] + sh[2] + sh[3];
    }
}

// ---------- Kernel 2 (partial path only): reduce partials -> column sums ----------
// grid (8,8): 64 blocks, each sums 64 partial rows for 256 cols, atomic finish.
__global__ __launch_bounds__(256) void k_reduce(float* __restrict__ ws) {
    const int col = blockIdx.x * 256 + threadIdx.x;
    const float* part = ws + WS_PART + (size_t)blockIdx.y * 64 * D_MODEL;
    float a0 = 0.f, a1 = 0.f, a2 = 0.f, a3 = 0.f;
    #pragma unroll 8
    for (int p = 0; p < 64; p += 4) {
        a0 += part[(size_t)(p + 0) * D_MODEL + col];
        a1 += part[(size_t)(p + 1) * D_MODEL + col];
        a2 += part[(size_t)(p + 2) * D_MODEL + col];
        a3 += part[(size_t)(p + 3) * D_MODEL + col];
    }
    atomicAdd(&ws[WS_SUMS + col], (a0 + a1) + (a2 + a3));
}

// ---------- Kernel 3: all matvecs, one wave per row ----------
// rows: [0,512) reg_proj | [512,1024) delta_proj | [1024,2560) upd (r then i) | [2560,2563) wg
__global__ __launch_bounds__(256) void k_matvec(const float* __restrict__ regs,
                                                const float* __restrict__ pa,
                                                const float* __restrict__ pd,
                                                const float* __restrict__ wr,
                                                const float* __restrict__ wi,
                                                const float* __restrict__ wgw,
                                                const float* __restrict__ wgb,
                                                const int* __restrict__ pidx,
                                                float* __restrict__ ws) {
    const int wid = threadIdx.x >> 6, lane = threadIdx.x & 63;
    const int row = blockIdx.x * 4 + wid;
    if (row >= TOTAL_ROWS) return;
    const int p = *pidx;

    const float* w; const float* x; int n4; int outIdx;
    float s = 0.f, post, bias = 0.f;
    bool tern = true;

    if (row < 512) {
        w = pa + (size_t)p * PA_N + (size_t)row * REG_FLAT;
        x = regs; n4 = REG_FLAT / 4;
        float a = (lane < 32) ? ws[WS_ABSP + lane] : 0.f;
        s = bfly(a) / (float)PA_N + EPSF;
        float q = 0.f;
        for (int i = lane; i < REG_FLAT / 4; i += 64) {
            f32x4 v = ((const f32x4*)regs)[i];
            q += v.x * v.x + v.y * v.y + v.z * v.z + v.w * v.w;
        }
        post = s / (sqrtf(bfly(q)) + EPSF);
        outIdx = WS_REGPROJ + row;
    } else if (row < 1024) {
        const int o = row - 512;
        w = pd + (size_t)p * PD_N + (size_t)o * D_MODEL;
        x = ws + WS_SUMS; n4 = D_MODEL / 4;
        float a = (lane < 32) ? ws[WS_ABSP + 32 + lane] : 0.f;
        s = bfly(a) / (float)PD_N + EPSF;
        float q = 0.f;
        for (int i = lane; i < D_MODEL / 4; i += 64) {
            f32x4 v = ((const f32x4*)(ws + WS_SUMS))[i];
            q += v.x * v.x + v.y * v.y + v.z * v.z + v.w * v.w;
        }
        // Wq @ (summary/(||summary||+eps)) == dot_q * s / (||sums|| + N*eps)
        post = s / (sqrtf(bfly(q)) + (float)N_ROWS * EPSF);
        outIdx = WS_DELTAPROJ + o;
    } else if (row < 2560) {
        const int t = row - 1024;                 // 0..1535
        const int half = t >= 768 ? 1 : 0;        // 0=real,1=imag
        const int tt = t - half * 768;            // 0..767
        const int r = tt >> 8;
        const int m = 2 + half * 3 + r;
        w = (half ? wi : wr) + (size_t)(p * 3 + r) * W_N + (size_t)(tt & 255) * D_MODEL;
        x = ws + WS_SUMS; n4 = D_MODEL / 4;
        float a = (lane < 32) ? ws[WS_ABSP + m * 32 + lane] : 0.f;
        s = bfly(a) / (float)W_N + EPSF;
        post = s / (float)N_ROWS;                 // summary = sums/N
        outIdx = WS_UPD + t;
    } else {
        const int i = row - 2560;
        const int mm = p * 3 + i;
        w = wgw + (size_t)mm * D_MODEL;
        x = ws + WS_SUMS; n4 = D_MODEL / 4;
        tern = false;
        post = 1.f / (float)N_ROWS;
        bias = wgb[mm];
        outIdx = WS_WG + i;
    }

    float acc = 0.f;
    if (tern) {
        const float inv_s = 1.0f / s;      // wave-uniform; replaces 4 divides/iter
        for (int i = lane; i < n4; i += 64) {
            f32x4 wv = __builtin_nontemporal_load(&((const f32x4*)w)[i]);
            f32x4 xv = ((const f32x4*)x)[i];
            float q0 = fmaxf(-1.f, fminf(1.f, rintf(wv.x * inv_s)));
            float q1 = fmaxf(-1.f, fminf(1.f, rintf(wv.y * inv_s)));
            float q2 = fmaxf(-1.f, fminf(1.f, rintf(wv.z * inv_s)));
            float q3 = fmaxf(-1.f, fminf(1.f, rintf(wv.w * inv_s)));
            acc += q0 * xv.x + q1 * xv.y + q2 * xv.z + q3 * xv.w;
        }
    } else {
        for (int i = lane; i < n4; i += 64) {
            f32x4 wv = __builtin_nontemporal_load(&((const f32x4*)w)[i]);
            f32x4 xv = ((const f32x4*)x)[i];
            acc += wv.x * xv.x + wv.y * xv.y + wv.z * xv.z + wv.w * xv.w;
        }
    }
    acc = bfly(acc);
    if (lane == 0) ws[outIdx] = acc * post + bias;
}

// ---------- Kernel 4: gated_delta = gate * delta (PLAIN load, NT store, fwd) ----------
// Finalize fused into block 0. All ws inputs were written by PREVIOUS kernels
// (dispatch boundary = coherent); every block recomputes gate locally (cheap).
__global__ __launch_bounds__(256) void k_scale(const f32x4* __restrict__ in,
                                               f32x4* __restrict__ out4,
                                               const float* __restrict__ ws,
                                               const float* __restrict__ regs,
                                               const float* __restrict__ temp,
                                               const float* __restrict__ lbias,
                                               const int* __restrict__ pidx,
                                               float* __restrict__ out) {
    const int tid = threadIdx.x;
    float a = 0.f;
    for (int i = tid; i < D_ALIGN; i += 256)
        a += ws[WS_REGPROJ + i] * ws[WS_DELTAPROJ + i];
    a = bfly(a);
    __shared__ float sh[4];
    if ((tid & 63) == 0) sh[tid >> 6] = a;
    __syncthreads();
    const int p = *pidx;
    const float align = sh[0] + sh[1] + sh[2] + sh[3];
    const float g = 1.f / (1.f + expf(-(align * temp[p] + lbias[p])));

    if (blockIdx.x == 0) {
        __shared__ float wg_s[N_REG];
        if (tid == 0) out[OUT_GATE] = g;
        if (tid < N_REG) {
            float v = 1.f / (1.f + expf(-ws[WS_WG + tid]));
            wg_s[tid] = v;
            out[OUT_WG + tid] = v;
        }
        __syncthreads();
        for (int t = tid; t < REG_FLAT; t += 256) {
            const int rk = t >> 1, c = t & 1;
            float u = ws[WS_UPD + c * 768 + rk];
            out[OUT_REGS + t] = regs[t] + wg_s[rk >> 8] * u;
        }
    }

    const size_t stride = (size_t)gridDim.x * 256;   // 524288 threads
    const size_t linear = (size_t)blockIdx.x * 256 + tid;
    #pragma unroll 4
    for (int j = 0; j < 32; ++j) {                   // 32 * 524288 * 4 = 64M floats
        const size_t i = linear + (size_t)j * stride;
        f32x4 v = in[i];
        v *= g;
        __builtin_nontemporal_store(v, &out4[i]);
    }
}

extern "C" void kernel_launch(void* const* d_in, const int* in_sizes, int n_in,
                              void* d_out, int out_size, void* d_ws, size_t ws_size,
                              hipStream_t stream) {
    (void)in_sizes; (void)n_in; (void)out_size;
    const float* delta = (const float*)d_in[0];
    const float* regs  = (const float*)d_in[1];
    const float* pa    = (const float*)d_in[2];
    const float* pd    = (const float*)d_in[3];
    const float* temp  = (const float*)d_in[4];
    const float* lbias = (const float*)d_in[5];
    const float* wr    = (const float*)d_in[6];
    const float* wi    = (const float*)d_in[7];
    const float* wgw   = (const float*)d_in[8];
    const float* wgb   = (const float*)d_in[9];
    const int*   pidx  = (const int*)d_in[10];
    float* out = (float*)d_out;
    float* ws  = (float*)d_ws;

    const int use_part = (ws_size >= WS_REQ_BYTES) ? 1 : 0;
    if (!use_part)
        hipMemsetAsync(d_ws, 0, D_MODEL * sizeof(float), stream);  // zero column sums

    k_stage1<<<NBY + 256, 256, 0, stream>>>(delta, pa, pd, wr, wi, pidx, ws, use_part);
    if (use_part)
        k_reduce<<<dim3(8, 8), 256, 0, stream>>>(ws);
    k_matvec<<<(TOTAL_ROWS + 3) / 4, 256, 0, stream>>>(regs, pa, pd, wr, wi,
                                                       wgw, wgb, pidx, ws);
    k_scale<<<2048, 256, 0, stream>>>((const f32x4*)delta, (f32x4*)d_out, ws,
                                      regs, temp, lbias, pidx, out);
}

// Round 9
// 162.466 us; speedup vs baseline: 1.2194x; 1.0107x over previous
//
#include <hip/hip_runtime.h>
#include <math.h>

typedef float f32x4 __attribute__((ext_vector_type(4)));

// Problem constants (fixed by setup_inputs)
#define D_MODEL   2048
#define N_ROWS    32768      // B*L
#define D_ALIGN   512
#define D_REG     256
#define N_REG     3
#define REG_FLAT  1536
#define EPSF      1e-8f

#define PA_N   (D_ALIGN * REG_FLAT)   // 786432
#define PD_N   (D_ALIGN * D_MODEL)    // 1048576
#define W_N    (D_REG * D_MODEL)      // 524288

// Output layout (flat f32): gated_delta | updated_registers | gate | wg
#define OUT_REGS  ((size_t)N_ROWS * D_MODEL)
#define OUT_GATE  (OUT_REGS + REG_FLAT)
#define OUT_WG    (OUT_GATE + 1)

// ws layout (floats)
#define WS_SUMS      0      // 2048 column sums of delta
#define WS_ABSP      2048   // 256 abs-sum partials: 8 matrices x 32 chunks
#define WS_REGPROJ   2304   // 512
#define WS_DELTAPROJ 2816   // 512
#define WS_UPD       3328   // 1536 (real 0..768, imag 768..1536)
#define WS_WG        4864   // 3
#define WS_PART      8192   // column-sum partials [NBY][2048]
#define NBY          512
#define WS_REQ_BYTES ((size_t)(WS_PART + NBY * D_MODEL) * sizeof(float))

#define TOTAL_ROWS    2563

__device__ __forceinline__ float bfly(float v) {
    #pragma unroll
    for (int o = 32; o > 0; o >>= 1) v += __shfl_xor(v, o, 64);
    return v;   // total in ALL lanes
}

// ---------- Kernel 1: colsum partials (blocks 0..511) + absmean partials (512..767) ----------
// delta: PLAIN loads (NT loads measured 2.5 TB/s in R7 — never on streams).
// weights: PLAIN loads (they ARE re-read by k_matvec right after -> warm L3).
__global__ __launch_bounds__(256) void k_stage1(const float* __restrict__ delta,
                                                const float* __restrict__ pa,
                                                const float* __restrict__ pd,
                                                const float* __restrict__ wr,
                                                const float* __restrict__ wi,
                                                const int* __restrict__ pidx,
                                                float* __restrict__ ws,
                                                int use_part) {
    const int b = blockIdx.x, t = threadIdx.x;
    if (b < NBY) {
        const f32x4* p = (const f32x4*)(delta + (size_t)b * 64 * D_MODEL);
        f32x4 a0  = {0.f, 0.f, 0.f, 0.f};
        f32x4 a0b = {0.f, 0.f, 0.f, 0.f};
        f32x4 a1  = {0.f, 0.f, 0.f, 0.f};
        f32x4 a1b = {0.f, 0.f, 0.f, 0.f};
        #pragma unroll 8
        for (int r = 0; r < 64; r += 2) {
            a0  += p[r * 512 + t];
            a1  += p[r * 512 + t + 256];
            a0b += p[(r + 1) * 512 + t];
            a1b += p[(r + 1) * 512 + t + 256];
        }
        a0 += a0b; a1 += a1b;
        if (use_part) {
            f32x4* part = (f32x4*)(ws + WS_PART);
            part[(size_t)b * 512 + t]       = a0;
            part[(size_t)b * 512 + t + 256] = a1;
        } else {
            atomicAdd(&ws[WS_SUMS + t * 4 + 0], a0.x);
            atomicAdd(&ws[WS_SUMS + t * 4 + 1], a0.y);
            atomicAdd(&ws[WS_SUMS + t * 4 + 2], a0.z);
            atomicAdd(&ws[WS_SUMS + t * 4 + 3], a0.w);
            atomicAdd(&ws[WS_SUMS + (t + 256) * 4 + 0], a1.x);
            atomicAdd(&ws[WS_SUMS + (t + 256) * 4 + 1], a1.y);
            atomicAdd(&ws[WS_SUMS + (t + 256) * 4 + 2], a1.z);
            atomicAdd(&ws[WS_SUMS + (t + 256) * 4 + 3], a1.w);
        }
    } else {
        const int idx = b - NBY;           // 0..255
        // zero WS_SUMS for k_reduce's atomic finish (visible at next dispatch)
        if (use_part && idx == 0) {
            for (int i = t; i < D_MODEL; i += 256) ws[WS_SUMS + i] = 0.f;
        }
        const int m = idx >> 5, chunk = idx & 31;
        const int pp = *pidx;
        const float* base; int n4;
        if (m == 0)      { base = pa + (size_t)pp * PA_N;                n4 = PA_N / 4; }
        else if (m == 1) { base = pd + (size_t)pp * PD_N;                n4 = PD_N / 4; }
        else if (m < 5)  { base = wr + (size_t)(pp * 3 + (m - 2)) * W_N; n4 = W_N / 4; }
        else             { base = wi + (size_t)(pp * 3 + (m - 5)) * W_N; n4 = W_N / 4; }
        const int per = n4 / 32;
        const int s = chunk * per, e = s + per;
        float acc = 0.f;
        for (int i = s + t; i < e; i += 256) {
            f32x4 v = ((const f32x4*)base)[i];     // plain: warm L3 for k_matvec
            acc += fabsf(v.x) + fabsf(v.y) + fabsf(v.z) + fabsf(v.w);
        }
        acc = bfly(acc);
        __shared__ float sh[4];
        if ((t & 63) == 0) sh[t >> 6] = acc;
        __syncthreads();
        if (t == 0) ws[WS_ABSP + idx] = sh[0] + sh[1] + sh[2] + sh[3];
    }
}

// ---------- Kernel 2 (partial path only): reduce partials -> column sums ----------
// grid (8,8): 64 blocks, each sums 64 partial rows for 256 cols, atomic finish.
__global__ __launch_bounds__(256) void k_reduce(float* __restrict__ ws) {
    const int col = blockIdx.x * 256 + threadIdx.x;
    const float* part = ws + WS_PART + (size_t)blockIdx.y * 64 * D_MODEL;
    float a0 = 0.f, a1 = 0.f, a2 = 0.f, a3 = 0.f;
    #pragma unroll 8
    for (int p = 0; p < 64; p += 4) {
        a0 += part[(size_t)(p + 0) * D_MODEL + col];
        a1 += part[(size_t)(p + 1) * D_MODEL + col];
        a2 += part[(size_t)(p + 2) * D_MODEL + col];
        a3 += part[(size_t)(p + 3) * D_MODEL + col];
    }
    atomicAdd(&ws[WS_SUMS + col], (a0 + a1) + (a2 + a3));
}

// ---------- Kernel 3: all matvecs, one wave per row (PLAIN loads — L3-warm) ----------
// rows: [0,512) reg_proj | [512,1024) delta_proj | [1024,2560) upd (r then i) | [2560,2563) wg
__global__ __launch_bounds__(256) void k_matvec(const float* __restrict__ regs,
                                                const float* __restrict__ pa,
                                                const float* __restrict__ pd,
                                                const float* __restrict__ wr,
                                                const float* __restrict__ wi,
                                                const float* __restrict__ wgw,
                                                const float* __restrict__ wgb,
                                                const int* __restrict__ pidx,
                                                float* __restrict__ ws) {
    const int wid = threadIdx.x >> 6, lane = threadIdx.x & 63;
    const int row = blockIdx.x * 4 + wid;
    if (row >= TOTAL_ROWS) return;
    const int p = *pidx;

    const float* w; const float* x; int n4; int outIdx;
    float s = 0.f, post, bias = 0.f;
    bool tern = true;

    if (row < 512) {
        w = pa + (size_t)p * PA_N + (size_t)row * REG_FLAT;
        x = regs; n4 = REG_FLAT / 4;
        float a = (lane < 32) ? ws[WS_ABSP + lane] : 0.f;
        s = bfly(a) / (float)PA_N + EPSF;
        float q = 0.f;
        for (int i = lane; i < REG_FLAT / 4; i += 64) {
            f32x4 v = ((const f32x4*)regs)[i];
            q += v.x * v.x + v.y * v.y + v.z * v.z + v.w * v.w;
        }
        post = s / (sqrtf(bfly(q)) + EPSF);
        outIdx = WS_REGPROJ + row;
    } else if (row < 1024) {
        const int o = row - 512;
        w = pd + (size_t)p * PD_N + (size_t)o * D_MODEL;
        x = ws + WS_SUMS; n4 = D_MODEL / 4;
        float a = (lane < 32) ? ws[WS_ABSP + 32 + lane] : 0.f;
        s = bfly(a) / (float)PD_N + EPSF;
        float q = 0.f;
        for (int i = lane; i < D_MODEL / 4; i += 64) {
            f32x4 v = ((const f32x4*)(ws + WS_SUMS))[i];
            q += v.x * v.x + v.y * v.y + v.z * v.z + v.w * v.w;
        }
        // Wq @ (summary/(||summary||+eps)) == dot_q * s / (||sums|| + N*eps)
        post = s / (sqrtf(bfly(q)) + (float)N_ROWS * EPSF);
        outIdx = WS_DELTAPROJ + o;
    } else if (row < 2560) {
        const int t = row - 1024;                 // 0..1535
        const int half = t >= 768 ? 1 : 0;        // 0=real,1=imag
        const int tt = t - half * 768;            // 0..767
        const int r = tt >> 8;
        const int m = 2 + half * 3 + r;
        w = (half ? wi : wr) + (size_t)(p * 3 + r) * W_N + (size_t)(tt & 255) * D_MODEL;
        x = ws + WS_SUMS; n4 = D_MODEL / 4;
        float a = (lane < 32) ? ws[WS_ABSP + m * 32 + lane] : 0.f;
        s = bfly(a) / (float)W_N + EPSF;
        post = s / (float)N_ROWS;                 // summary = sums/N
        outIdx = WS_UPD + t;
    } else {
        const int i = row - 2560;
        const int mm = p * 3 + i;
        w = wgw + (size_t)mm * D_MODEL;
        x = ws + WS_SUMS; n4 = D_MODEL / 4;
        tern = false;
        post = 1.f / (float)N_ROWS;
        bias = wgb[mm];
        outIdx = WS_WG + i;
    }

    float acc = 0.f;
    if (tern) {
        const float inv_s = 1.0f / s;      // wave-uniform; replaces 4 divides/iter
        for (int i = lane; i < n4; i += 64) {
            f32x4 wv = ((const f32x4*)w)[i];
            f32x4 xv = ((const f32x4*)x)[i];
            float q0 = fmaxf(-1.f, fminf(1.f, rintf(wv.x * inv_s)));
            float q1 = fmaxf(-1.f, fminf(1.f, rintf(wv.y * inv_s)));
            float q2 = fmaxf(-1.f, fminf(1.f, rintf(wv.z * inv_s)));
            float q3 = fmaxf(-1.f, fminf(1.f, rintf(wv.w * inv_s)));
            acc += q0 * xv.x + q1 * xv.y + q2 * xv.z + q3 * xv.w;
        }
    } else {
        for (int i = lane; i < n4; i += 64) {
            f32x4 wv = ((const f32x4*)w)[i];
            f32x4 xv = ((const f32x4*)x)[i];
            acc += wv.x * xv.x + wv.y * xv.y + wv.z * xv.z + wv.w * xv.w;
        }
    }
    acc = bfly(acc);
    if (lane == 0) ws[outIdx] = acc * post + bias;
}

// ---------- Kernel 4: gated_delta = gate * delta (PLAIN load, NT store, fwd) ----------
// 8192 blocks x 8 fully-unrolled iters: max TLP for the mixed R/W stream.
// Finalize fused into block 0 (ws written by previous dispatches = coherent).
__global__ __launch_bounds__(256) void k_scale(const f32x4* __restrict__ in,
                                               f32x4* __restrict__ out4,
                                               const float* __restrict__ ws,
                                               const float* __restrict__ regs,
                                               const float* __restrict__ temp,
                                               const float* __restrict__ lbias,
                                               const int* __restrict__ pidx,
                                               float* __restrict__ out) {
    const int tid = threadIdx.x;
    float a = 0.f;
    for (int i = tid; i < D_ALIGN; i += 256)
        a += ws[WS_REGPROJ + i] * ws[WS_DELTAPROJ + i];
    a = bfly(a);
    __shared__ float sh[4];
    if ((tid & 63) == 0) sh[tid >> 6] = a;
    __syncthreads();
    const int p = *pidx;
    const float align = sh[0] + sh[1] + sh[2] + sh[3];
    const float g = 1.f / (1.f + expf(-(align * temp[p] + lbias[p])));

    if (blockIdx.x == 0) {
        __shared__ float wg_s[N_REG];
        if (tid == 0) out[OUT_GATE] = g;
        if (tid < N_REG) {
            float v = 1.f / (1.f + expf(-ws[WS_WG + tid]));
            wg_s[tid] = v;
            out[OUT_WG + tid] = v;
        }
        __syncthreads();
        for (int t = tid; t < REG_FLAT; t += 256) {
            const int rk = t >> 1, c = t & 1;
            float u = ws[WS_UPD + c * 768 + rk];
            out[OUT_REGS + t] = regs[t] + wg_s[rk >> 8] * u;
        }
    }

    const size_t stride = (size_t)gridDim.x * 256;   // 8192*256 = 2097152 threads
    const size_t linear = (size_t)blockIdx.x * 256 + tid;
    #pragma unroll
    for (int j = 0; j < 8; ++j) {                    // 8 * 2097152 * 4 = 64M floats
        const size_t i = linear + (size_t)j * stride;
        f32x4 v = in[i];
        v *= g;
        __builtin_nontemporal_store(v, &out4[i]);
    }
}

extern "C" void kernel_launch(void* const* d_in, const int* in_sizes, int n_in,
                              void* d_out, int out_size, void* d_ws, size_t ws_size,
                              hipStream_t stream) {
    (void)in_sizes; (void)n_in; (void)out_size;
    const float* delta = (const float*)d_in[0];
    const float* regs  = (const float*)d_in[1];
    const float* pa    = (const float*)d_in[2];
    const float* pd    = (const float*)d_in[3];
    const float* temp  = (const float*)d_in[4];
    const float* lbias = (const float*)d_in[5];
    const float* wr    = (const float*)d_in[6];
    const float* wi    = (const float*)d_in[7];
    const float* wgw   = (const float*)d_in[8];
    const float* wgb   = (const float*)d_in[9];
    const int*   pidx  = (const int*)d_in[10];
    float* out = (float*)d_out;
    float* ws  = (float*)d_ws;

    const int use_part = (ws_size >= WS_REQ_BYTES) ? 1 : 0;
    if (!use_part)
        hipMemsetAsync(d_ws, 0, D_MODEL * sizeof(float), stream);  // zero column sums

    k_stage1<<<NBY + 256, 256, 0, stream>>>(delta, pa, pd, wr, wi, pidx, ws, use_part);
    if (use_part)
        k_reduce<<<dim3(8, 8), 256, 0, stream>>>(ws);
    k_matvec<<<(TOTAL_ROWS + 3) / 4, 256, 0, stream>>>(regs, pa, pd, wr, wi,
                                                       wgw, wgb, pidx, ws);
    k_scale<<<8192, 256, 0, stream>>>((const f32x4*)delta, (f32x4*)d_out, ws,
                                      regs, temp, lbias, pidx, out);
}

// Round 10
// 150.735 us; speedup vs baseline: 1.3143x; 1.0778x over previous
//
#include <hip/hip_runtime.h>
#include <math.h>

typedef float f32x4 __attribute__((ext_vector_type(4)));

// Problem constants (fixed by setup_inputs)
#define D_MODEL   2048
#define N_ROWS    32768      // B*L
#define D_ALIGN   512
#define D_REG     256
#define N_REG     3
#define REG_FLAT  1536
#define EPSF      1e-8f

#define PA_N   (D_ALIGN * REG_FLAT)   // 786432
#define PD_N   (D_ALIGN * D_MODEL)    // 1048576
#define W_N    (D_REG * D_MODEL)      // 524288

// Output layout (flat f32): gated_delta | updated_registers | gate | wg
#define OUT_REGS  ((size_t)N_ROWS * D_MODEL)
#define OUT_GATE  (OUT_REGS + REG_FLAT)
#define OUT_WG    (OUT_GATE + 1)

// ws layout (floats)
#define WS_SUMS      0      // 2048 column sums of delta
#define WS_ABSP      2048   // 256 abs-sum partials: 8 matrices x 32 chunks
#define WS_REGPROJ   2304   // 512
#define WS_DELTAPROJ 2816   // 512
#define WS_UPD       3328   // 1536 (real 0..768, imag 768..1536)
#define WS_WG        4864   // 3
#define WS_PART      8192   // column-sum partials [NBY][2048]
#define NBY          512
#define WS_REQ_BYTES ((size_t)(WS_PART + NBY * D_MODEL) * sizeof(float))

#define TOTAL_ROWS    2563

__device__ __forceinline__ float bfly(float v) {
    #pragma unroll
    for (int o = 32; o > 0; o >>= 1) v += __shfl_xor(v, o, 64);
    return v;   // total in ALL lanes
}

// ---------- Kernel 1: colsum partials (blocks 0..511) + absmean partials (512..767) ----------
// delta: PLAIN loads (NT loads measured 2.5 TB/s in R7 — never on streams).
// weights: PLAIN loads (they ARE re-read by k_matvec right after -> warm L3).
__global__ __launch_bounds__(256) void k_stage1(const float* __restrict__ delta,
                                                const float* __restrict__ pa,
                                                const float* __restrict__ pd,
                                                const float* __restrict__ wr,
                                                const float* __restrict__ wi,
                                                const int* __restrict__ pidx,
                                                float* __restrict__ ws,
                                                int use_part) {
    const int b = blockIdx.x, t = threadIdx.x;
    if (b < NBY) {
        const f32x4* p = (const f32x4*)(delta + (size_t)b * 64 * D_MODEL);
        f32x4 a0  = {0.f, 0.f, 0.f, 0.f};
        f32x4 a0b = {0.f, 0.f, 0.f, 0.f};
        f32x4 a1  = {0.f, 0.f, 0.f, 0.f};
        f32x4 a1b = {0.f, 0.f, 0.f, 0.f};
        #pragma unroll 8
        for (int r = 0; r < 64; r += 2) {
            a0  += p[r * 512 + t];
            a1  += p[r * 512 + t + 256];
            a0b += p[(r + 1) * 512 + t];
            a1b += p[(r + 1) * 512 + t + 256];
        }
        a0 += a0b; a1 += a1b;
        if (use_part) {
            f32x4* part = (f32x4*)(ws + WS_PART);
            part[(size_t)b * 512 + t]       = a0;
            part[(size_t)b * 512 + t + 256] = a1;
        } else {
            atomicAdd(&ws[WS_SUMS + t * 4 + 0], a0.x);
            atomicAdd(&ws[WS_SUMS + t * 4 + 1], a0.y);
            atomicAdd(&ws[WS_SUMS + t * 4 + 2], a0.z);
            atomicAdd(&ws[WS_SUMS + t * 4 + 3], a0.w);
            atomicAdd(&ws[WS_SUMS + (t + 256) * 4 + 0], a1.x);
            atomicAdd(&ws[WS_SUMS + (t + 256) * 4 + 1], a1.y);
            atomicAdd(&ws[WS_SUMS + (t + 256) * 4 + 2], a1.z);
            atomicAdd(&ws[WS_SUMS + (t + 256) * 4 + 3], a1.w);
        }
    } else {
        const int idx = b - NBY;           // 0..255
        // zero WS_SUMS for k_reduce's atomic finish (visible at next dispatch)
        if (use_part && idx == 0) {
            for (int i = t; i < D_MODEL; i += 256) ws[WS_SUMS + i] = 0.f;
        }
        const int m = idx >> 5, chunk = idx & 31;
        const int pp = *pidx;
        const float* base; int n4;
        if (m == 0)      { base = pa + (size_t)pp * PA_N;                n4 = PA_N / 4; }
        else if (m == 1) { base = pd + (size_t)pp * PD_N;                n4 = PD_N / 4; }
        else if (m < 5)  { base = wr + (size_t)(pp * 3 + (m - 2)) * W_N; n4 = W_N / 4; }
        else             { base = wi + (size_t)(pp * 3 + (m - 5)) * W_N; n4 = W_N / 4; }
        const int per = n4 / 32;
        const int s = chunk * per, e = s + per;
        float acc = 0.f;
        for (int i = s + t; i < e; i += 256) {
            f32x4 v = ((const f32x4*)base)[i];     // plain: warm L3 for k_matvec
            acc += fabsf(v.x) + fabsf(v.y) + fabsf(v.z) + fabsf(v.w);
        }
        acc = bfly(acc);
        __shared__ float sh[4];
        if ((t & 63) == 0) sh[t >> 6] = acc;
        __syncthreads();
        if (t == 0) ws[WS_ABSP + idx] = sh[0] + sh[1] + sh[2] + sh[3];
    }
}

// ---------- Kernel 2 (partial path only): reduce partials -> column sums ----------
// grid (8,8): 64 blocks, each sums 64 partial rows for 256 cols, atomic finish.
__global__ __launch_bounds__(256) void k_reduce(float* __restrict__ ws) {
    const int col = blockIdx.x * 256 + threadIdx.x;
    const float* part = ws + WS_PART + (size_t)blockIdx.y * 64 * D_MODEL;
    float a0 = 0.f, a1 = 0.f, a2 = 0.f, a3 = 0.f;
    #pragma unroll 8
    for (int p = 0; p < 64; p += 4) {
        a0 += part[(size_t)(p + 0) * D_MODEL + col];
        a1 += part[(size_t)(p + 1) * D_MODEL + col];
        a2 += part[(size_t)(p + 2) * D_MODEL + col];
        a3 += part[(size_t)(p + 3) * D_MODEL + col];
    }
    atomicAdd(&ws[WS_SUMS + col], (a0 + a1) + (a2 + a3));
}

// ---------- Kernel 3: all matvecs, one wave per row (PLAIN loads — L3-warm) ----------
// rows: [0,512) reg_proj | [512,1024) delta_proj | [1024,2560) upd (r then i) | [2560,2563) wg
__global__ __launch_bounds__(256) void k_matvec(const float* __restrict__ regs,
                                                const float* __restrict__ pa,
                                                const float* __restrict__ pd,
                                                const float* __restrict__ wr,
                                                const float* __restrict__ wi,
                                                const float* __restrict__ wgw,
                                                const float* __restrict__ wgb,
                                                const int* __restrict__ pidx,
                                                float* __restrict__ ws) {
    const int wid = threadIdx.x >> 6, lane = threadIdx.x & 63;
    const int row = blockIdx.x * 4 + wid;
    if (row >= TOTAL_ROWS) return;
    const int p = *pidx;

    const float* w; const float* x; int n4; int outIdx;
    float s = 0.f, post, bias = 0.f;
    bool tern = true;

    if (row < 512) {
        w = pa + (size_t)p * PA_N + (size_t)row * REG_FLAT;
        x = regs; n4 = REG_FLAT / 4;
        float a = (lane < 32) ? ws[WS_ABSP + lane] : 0.f;
        s = bfly(a) / (float)PA_N + EPSF;
        float q = 0.f;
        for (int i = lane; i < REG_FLAT / 4; i += 64) {
            f32x4 v = ((const f32x4*)regs)[i];
            q += v.x * v.x + v.y * v.y + v.z * v.z + v.w * v.w;
        }
        post = s / (sqrtf(bfly(q)) + EPSF);
        outIdx = WS_REGPROJ + row;
    } else if (row < 1024) {
        const int o = row - 512;
        w = pd + (size_t)p * PD_N + (size_t)o * D_MODEL;
        x = ws + WS_SUMS; n4 = D_MODEL / 4;
        float a = (lane < 32) ? ws[WS_ABSP + 32 + lane] : 0.f;
        s = bfly(a) / (float)PD_N + EPSF;
        float q = 0.f;
        for (int i = lane; i < D_MODEL / 4; i += 64) {
            f32x4 v = ((const f32x4*)(ws + WS_SUMS))[i];
            q += v.x * v.x + v.y * v.y + v.z * v.z + v.w * v.w;
        }
        // Wq @ (summary/(||summary||+eps)) == dot_q * s / (||sums|| + N*eps)
        post = s / (sqrtf(bfly(q)) + (float)N_ROWS * EPSF);
        outIdx = WS_DELTAPROJ + o;
    } else if (row < 2560) {
        const int t = row - 1024;                 // 0..1535
        const int half = t >= 768 ? 1 : 0;        // 0=real,1=imag
        const int tt = t - half * 768;            // 0..767
        const int r = tt >> 8;
        const int m = 2 + half * 3 + r;
        w = (half ? wi : wr) + (size_t)(p * 3 + r) * W_N + (size_t)(tt & 255) * D_MODEL;
        x = ws + WS_SUMS; n4 = D_MODEL / 4;
        float a = (lane < 32) ? ws[WS_ABSP + m * 32 + lane] : 0.f;
        s = bfly(a) / (float)W_N + EPSF;
        post = s / (float)N_ROWS;                 // summary = sums/N
        outIdx = WS_UPD + t;
    } else {
        const int i = row - 2560;
        const int mm = p * 3 + i;
        w = wgw + (size_t)mm * D_MODEL;
        x = ws + WS_SUMS; n4 = D_MODEL / 4;
        tern = false;
        post = 1.f / (float)N_ROWS;
        bias = wgb[mm];
        outIdx = WS_WG + i;
    }

    float acc = 0.f;
    if (tern) {
        const float inv_s = 1.0f / s;      // wave-uniform; replaces 4 divides/iter
        for (int i = lane; i < n4; i += 64) {
            f32x4 wv = ((const f32x4*)w)[i];
            f32x4 xv = ((const f32x4*)x)[i];
            float q0 = fmaxf(-1.f, fminf(1.f, rintf(wv.x * inv_s)));
            float q1 = fmaxf(-1.f, fminf(1.f, rintf(wv.y * inv_s)));
            float q2 = fmaxf(-1.f, fminf(1.f, rintf(wv.z * inv_s)));
            float q3 = fmaxf(-1.f, fminf(1.f, rintf(wv.w * inv_s)));
            acc += q0 * xv.x + q1 * xv.y + q2 * xv.z + q3 * xv.w;
        }
    } else {
        for (int i = lane; i < n4; i += 64) {
            f32x4 wv = ((const f32x4*)w)[i];
            f32x4 xv = ((const f32x4*)x)[i];
            acc += wv.x * xv.x + wv.y * xv.y + wv.z * xv.z + wv.w * xv.w;
        }
    }
    acc = bfly(acc);
    if (lane == 0) ws[outIdx] = acc * post + bias;
}

// ---------- Kernel 4: gated_delta = gate * delta (PLAIN load, NT store) ----------
// Per-block CONTIGUOUS 32 KB chunk (like the 6.9 TB/s fill kernel), sequential
// within the block: best DRAM page/channel locality. Finalize fused in block 0.
__global__ __launch_bounds__(256) void k_scale(const f32x4* __restrict__ in,
                                               f32x4* __restrict__ out4,
                                               const float* __restrict__ ws,
                                               const float* __restrict__ regs,
                                               const float* __restrict__ temp,
                                               const float* __restrict__ lbias,
                                               const int* __restrict__ pidx,
                                               float* __restrict__ out) {
    const int tid = threadIdx.x;
    float a = 0.f;
    for (int i = tid; i < D_ALIGN; i += 256)
        a += ws[WS_REGPROJ + i] * ws[WS_DELTAPROJ + i];
    a = bfly(a);
    __shared__ float sh[4];
    if ((tid & 63) == 0) sh[tid >> 6] = a;
    __syncthreads();
    const int p = *pidx;
    const float align = sh[0] + sh[1] + sh[2] + sh[3];
    const float g = 1.f / (1.f + expf(-(align * temp[p] + lbias[p])));

    if (blockIdx.x == 0) {
        __shared__ float wg_s[N_REG];
        if (tid == 0) out[OUT_GATE] = g;
        if (tid < N_REG) {
            float v = 1.f / (1.f + expf(-ws[WS_WG + tid]));
            wg_s[tid] = v;
            out[OUT_WG + tid] = v;
        }
        __syncthreads();
        for (int t = tid; t < REG_FLAT; t += 256) {
            const int rk = t >> 1, c = t & 1;
            float u = ws[WS_UPD + c * 768 + rk];
            out[OUT_REGS + t] = regs[t] + wg_s[rk >> 8] * u;
        }
    }

    // 8192 blocks x 2048 f32x4 contiguous each (32 KB/block)
    const size_t base = (size_t)blockIdx.x * 2048 + tid;
    #pragma unroll
    for (int j = 0; j < 8; ++j) {
        const size_t i = base + j * 256;
        f32x4 v = in[i];
        v *= g;
        __builtin_nontemporal_store(v, &out4[i]);
    }
}

extern "C" void kernel_launch(void* const* d_in, const int* in_sizes, int n_in,
                              void* d_out, int out_size, void* d_ws, size_t ws_size,
                              hipStream_t stream) {
    (void)in_sizes; (void)n_in; (void)out_size;
    const float* delta = (const float*)d_in[0];
    const float* regs  = (const float*)d_in[1];
    const float* pa    = (const float*)d_in[2];
    const float* pd    = (const float*)d_in[3];
    const float* temp  = (const float*)d_in[4];
    const float* lbias = (const float*)d_in[5];
    const float* wr    = (const float*)d_in[6];
    const float* wi    = (const float*)d_in[7];
    const float* wgw   = (const float*)d_in[8];
    const float* wgb   = (const float*)d_in[9];
    const int*   pidx  = (const int*)d_in[10];
    float* out = (float*)d_out;
    float* ws  = (float*)d_ws;

    const int use_part = (ws_size >= WS_REQ_BYTES) ? 1 : 0;
    if (!use_part)
        hipMemsetAsync(d_ws, 0, D_MODEL * sizeof(float), stream);  // zero column sums

    k_stage1<<<NBY + 256, 256, 0, stream>>>(delta, pa, pd, wr, wi, pidx, ws, use_part);
    if (use_part)
        k_reduce<<<dim3(8, 8), 256, 0, stream>>>(ws);
    k_matvec<<<(TOTAL_ROWS + 3) / 4, 256, 0, stream>>>(regs, pa, pd, wr, wi,
                                                       wgw, wgb, pidx, ws);
    k_scale<<<8192, 256, 0, stream>>>((const f32x4*)delta, (f32x4*)d_out, ws,
                                      regs, temp, lbias, pidx, out);
}